// Round 8
// baseline (8006.503 us; speedup 1.0000x reference)
//
#include <hip/hip_runtime.h>
#include <hip/hip_bf16.h>

// CustomLMHead: C[M,N] = X[M,K] @ (Wq[N,K] * scale[N])^T
// M=2048, N=151936, K=896.
//
// Fast path: preconvert X(fp32)->bf16, Wq(int32)->bf16 into d_ws, then an
// A-DIRECT GEMM: 128x128 tile, 4 waves; A fragments load global->VGPR
// (L2-resident, 1-tile prefetch, even/odd reg sets); B triple-buffered in
// 24 KiB LDS via global_load_lds (T2 swizzle); ONE barrier per K-tile with
// counted vmcnt (vmcnt -> barrier -> read discipline for B); 6 blocks/CU.
// Coalesced LDS epilogue (4 passes of [32][128] f32).
// Fallback (small ws): reg-staging kernel with in-loop conversion.

#define M_DIM 2048
#define N_DIM 151936
#define K_DIM 896

#define BM 128
#define BN 128
#define BK 32
#define NKT (K_DIM / BK)        // 28
#define MB_CNT (M_DIM / BM)     // 16
#define NB_CNT (N_DIM / BN)     // 1187 (exact)
#define NWG (MB_CNT * NB_CNT)   // 18992, divisible by 8

typedef __attribute__((ext_vector_type(8))) short bf16x8;
typedef __attribute__((ext_vector_type(4))) float f32x4;
typedef __attribute__((ext_vector_type(4))) int   i32x4;
typedef __attribute__((ext_vector_type(4))) unsigned int u32x4;

static __device__ __forceinline__ unsigned short f2bf(float f) {
    unsigned int u = __builtin_bit_cast(unsigned int, f);
    u += 0x7FFFu + ((u >> 16) & 1u);
    return (unsigned short)(u >> 16);
}
static __device__ __forceinline__ unsigned int pack2(float lo, float hi) {
    return (unsigned int)f2bf(lo) | ((unsigned int)f2bf(hi) << 16);
}
static __device__ __forceinline__ void gload_lds16(const void* g, void* l) {
    __builtin_amdgcn_global_load_lds(
        (const __attribute__((address_space(1))) unsigned int*)g,
        (__attribute__((address_space(3))) unsigned int*)l, 16, 0, 0);
}

// ---------------- preconvert kernels ----------------

__global__ void cvt_x_kernel(const float* __restrict__ X,
                             unsigned short* __restrict__ Xb) {
    const long n8 = (long)M_DIM * K_DIM / 8;
    for (long i = (long)blockIdx.x * blockDim.x + threadIdx.x; i < n8;
         i += (long)gridDim.x * blockDim.x) {
        f32x4 a = ((const f32x4*)X)[2 * i];
        f32x4 b = ((const f32x4*)X)[2 * i + 1];
        u32x4 o;
        o[0] = pack2(a[0], a[1]); o[1] = pack2(a[2], a[3]);
        o[2] = pack2(b[0], b[1]); o[3] = pack2(b[2], b[3]);
        ((u32x4*)Xb)[i] = o;
    }
}

__global__ void cvt_w_kernel(const int* __restrict__ Wq,
                             unsigned short* __restrict__ Wb) {
    const long n8 = (long)N_DIM * K_DIM / 8;
    for (long i = (long)blockIdx.x * blockDim.x + threadIdx.x; i < n8;
         i += (long)gridDim.x * blockDim.x) {
        i32x4 a = ((const i32x4*)Wq)[2 * i];
        i32x4 b = ((const i32x4*)Wq)[2 * i + 1];
        u32x4 o;
        o[0] = pack2((float)a[0], (float)a[1]); o[1] = pack2((float)a[2], (float)a[3]);
        o[2] = pack2((float)b[0], (float)b[1]); o[3] = pack2((float)b[2], (float)b[3]);
        ((u32x4*)Wb)[i] = o;
    }
}

// ---------------- A-direct 128x128 GEMM ----------------
// Per tile t (B buf = t%3), ONE barrier:
//   pre:  READ_B(buf t) 4 ds_read; A-prefetch(t+1) 4 global->reg;
//         stage B(t+2) 2 gload_lds; SCHED0; VMCNT(6); LGKM0; SCHED0; BAR; SCHED0
//   post: 16 MFMA (setprio) using A(t) regs.
// FIFO at tile t's wait (issue order pinned by SCHED0 fences):
//   outstanding = A(t)4, B(t+1)2, A(t+1)4, B(t+2)2 -> vmcnt(6) retires
//   A(t) (needed now) AND B(t+1) (published by THIS barrier, read at t+1
//   after the barrier: valid vmcnt->barrier->read happens-before).
// WAR: my B(t) ds_reads drained (LGKM0) before the barrier; buf t%3 is
//   overwritten by the stage issued at t+1 (after this barrier).
// Tails: t=NKT-2 no stage -> VMCNT(4) (retires A(t)+B(t+1));
//        t=NKT-1 reads-only, no barrier (epilogue __syncthreads follows).

#define SCHED0 __builtin_amdgcn_sched_barrier(0)
#define VMCNT(N) asm volatile("s_waitcnt vmcnt(" #N ")" ::: "memory")
#define LGKM0    asm volatile("s_waitcnt lgkmcnt(0)" ::: "memory")

__global__ __launch_bounds__(256, 6)
void lmhead_gemm_ad(const unsigned short* __restrict__ Xb,
                    const unsigned short* __restrict__ Wb,
                    const float* __restrict__ S,
                    float* __restrict__ O)
{
    __shared__ unsigned short Blds[3][BN][BK];   // 24 KiB

    const int tid  = threadIdx.x;
    const int lane = tid & 63;
    const int wave = tid >> 6;      // 0..3
    const int wr   = wave >> 1;     // 0..1
    const int wc   = wave & 1;      // 0..1

    // XCD-chunked bijective swizzle; mb fastest so the 16 m-blocks sharing
    // one 128-row W strip (and the whole 3.5MB A) co-locate on one XCD's L2.
    const int bid = blockIdx.x;
    const int wg  = (bid & 7) * (NWG / 8) + (bid >> 3);
    const int mb  = wg % MB_CNT;
    const int nb  = wg / MB_CNT;

    // ---- B staging (gload_lds, T2 swizzle) ----
    // per instr: wave covers 16 rows; dest row = base + (lane>>2), phys
    // 16B-slot = lane&3; swizzle phys = logical ^ ((row>>1)&3)
    // -> source slot = (lane&3) ^ ((lane>>3)&3).
    const int lslot = (lane & 3) ^ ((lane >> 3) & 3);
    const unsigned short* srcB0 =
        Wb + (size_t)(nb * BN + wave * 16 + (lane >> 2)) * K_DIM + lslot * 8;
    const unsigned short* srcB1 = srcB0 + (size_t)64 * K_DIM;

    auto stageB = [&](int b3, int k0) {
        gload_lds16(srcB0 + k0, &Blds[b3][wave * 16][0]);
        gload_lds16(srcB1 + k0, &Blds[b3][64 + wave * 16][0]);
    };

    // ---- A direct global->reg (no swizzle; exact MFMA fragment layout) ----
    // lane reads row = wr*64 + (lane&15) + i*16 (i=0..3), k-octet = lane>>4.
    const unsigned short* aPtr =
        Xb + (size_t)(mb * BM + wr * 64 + (lane & 15)) * K_DIM + (lane >> 4) * 8;

    // ---- B fragment reads: row = wc*64 + nf*16 + (lane&15);
    //      phys octet = (lane>>4) ^ ((lane>>1)&3)  (2-way banks = free) ----
    const int physoff   = ((lane >> 4) ^ ((lane >> 1) & 3)) * 8;
    const int brow_base = wc * 64 + (lane & 15);

    f32x4 acc[4][4];
    #pragma unroll
    for (int i = 0; i < 4; ++i)
        #pragma unroll
        for (int j = 0; j < 4; ++j)
            acc[i][j] = f32x4{0.f, 0.f, 0.f, 0.f};

    bf16x8 aE[4], aO[4], bFr[4];

    // prologue: B(0)->buf0, B(1)->buf1, A(0)->aE; retire+publish B(0),B(1)
    stageB(0, 0);
    stageB(1, BK);
    #pragma unroll
    for (int i = 0; i < 4; ++i)
        aE[i] = *(const bf16x8*)&aPtr[(size_t)i * 16 * K_DIM];
    SCHED0; VMCNT(4); SCHED0;
    __builtin_amdgcn_s_barrier();
    SCHED0;

#define READ_BF(C3) do { \
    _Pragma("unroll") \
    for (int nf = 0; nf < 4; ++nf) \
        bFr[nf] = *(const bf16x8*)&Blds[C3][brow_base + nf * 16][physoff]; \
} while (0)
#define LOAD_A(DST, T1) do { \
    _Pragma("unroll") \
    for (int i = 0; i < 4; ++i) \
        DST[i] = *(const bf16x8*)&aPtr[(size_t)i * 16 * K_DIM + (T1) * BK]; \
} while (0)
#define MFMA16(AC) do { \
    __builtin_amdgcn_s_setprio(1); \
    _Pragma("unroll") \
    for (int mi = 0; mi < 4; ++mi) { \
        _Pragma("unroll") \
        for (int nf = 0; nf < 4; ++nf) \
            acc[mi][nf] = __builtin_amdgcn_mfma_f32_16x16x32_bf16( \
                AC[mi], bFr[nf], acc[mi][nf], 0, 0, 0); \
    } \
    __builtin_amdgcn_s_setprio(0); \
} while (0)
#define TILE_FULL(T, C0, C2, ACUR, ANXT) do { \
    READ_BF(C0); \
    LOAD_A(ANXT, (T) + 1); \
    stageB(C2, ((T) + 2) * BK); \
    SCHED0; VMCNT(6); LGKM0; SCHED0; \
    __builtin_amdgcn_s_barrier(); \
    SCHED0; \
    MFMA16(ACUR); \
} while (0)
#define ROT() do { int _tmp = c0; c0 = c1; c1 = c2; c2 = _tmp; } while (0)

    int c0 = 0, c1 = 1, c2 = 2;   // c0 = t%3
    for (int tt = 0; tt < NKT - 2; tt += 2) {   // t = 0..25
        TILE_FULL(tt, c0, c2, aE, aO);
        ROT();
        TILE_FULL(tt + 1, c0, c2, aO, aE);
        ROT();
    }
    // t = NKT-2 = 26 (even -> aCur = aE): load A(27), no stage, VMCNT(4)
    {
        READ_BF(c0);
        LOAD_A(aO, NKT - 1);
        SCHED0; VMCNT(4); LGKM0; SCHED0;
        __builtin_amdgcn_s_barrier();
        SCHED0;
        MFMA16(aE);
        ROT();
    }
    // t = NKT-1 = 27: reads only (B published at t=26's barrier); no barrier
    {
        READ_BF(c0);
        MFMA16(aO);
    }

#undef READ_BF
#undef LOAD_A
#undef MFMA16
#undef TILE_FULL
#undef ROT

    // ---- LDS-coalesced epilogue: 4 passes of float[32][128] (16 KiB) ----
    // Writes: scaled, XOR-swizzled pcol = col ^ (qw<<4) (2-way = free).
    // Reads: f32x4 contiguous -> full 128B-line global row stores.
    __syncthreads();   // all K-loop LDS reads drained before reuse

    float* lf = (float*)&Blds[0][0][0];
    const int qw = lane >> 4;     // 0..3
    const int li = lane & 15;

    float scn[4];
    #pragma unroll
    for (int nf = 0; nf < 4; ++nf)
        scn[nf] = S[nb * BN + wc * 64 + nf * 16 + li];

    #pragma unroll
    for (int p = 0; p < 4; ++p) {
        if (p) __syncthreads();   // prev pass reads done before overwrite
        if (wr == (p >> 1)) {
            #pragma unroll
            for (int al = 0; al < 2; ++al) {
                const int a = (p & 1) * 2 + al;
                #pragma unroll
                for (int nf = 0; nf < 4; ++nf) {
                    #pragma unroll
                    for (int r = 0; r < 4; ++r) {
                        const int lr   = al * 16 + qw * 4 + r;   // 0..31
                        const int col  = wc * 64 + nf * 16 + li;
                        const int pcol = col ^ (qw << 4);
                        lf[lr * 128 + pcol] = acc[a][nf][r] * scn[nf];
                    }
                }
            }
        }
        __syncthreads();
        #pragma unroll
        for (int i = 0; i < 4; ++i) {
            const int row = i * 8 + (tid >> 5);        // 0..31
            const int q   = (row >> 2) & 3;
            const int pc4 = (tid & 31) ^ (q << 2);
            f32x4 v = *(const f32x4*)&lf[row * 128 + pc4 * 4];
            const size_t grow = (size_t)(mb * BM + p * 32 + row);
            const size_t gcol = (size_t)(nb * BN + (tid & 31) * 4);
            *(f32x4*)&O[grow * N_DIM + gcol] = v;
        }
    }
}

// ---------------- fallback: reg staging + in-loop convert ----------------

#define FBM 128
#define FBN 128
#define FBK 32
#define FNSTEPS (K_DIM / FBK)
#define FMB (M_DIM / FBM)
#define FNB (N_DIM / FBN)
#define FNWG (FMB * FNB)

__global__ __launch_bounds__(256, 2)
void lmhead_gemm_conv(const float* __restrict__ X,
                      const int* __restrict__ Wq,
                      const float* __restrict__ S,
                      float* __restrict__ O)
{
    __shared__ unsigned short Alds[2][FBM][FBK];
    __shared__ unsigned short Blds2[2][FBN][FBK];

    const int tid  = threadIdx.x;
    const int lane = tid & 63;
    const int wave = tid >> 6;
    const int wr   = wave >> 1;
    const int wc   = wave & 1;

    const int bid = blockIdx.x;
    const int wg  = (bid & 7) * (FNWG / 8) + (bid >> 3);
    const int mb  = wg % FMB;
    const int nb  = wg / FMB;

    const int srow = tid >> 1;
    const int skh  = (tid & 1) * 16;

    const float* aptr = X  + (size_t)(mb * FBM + srow) * K_DIM + skh;
    const int*   wptr = Wq + (size_t)(nb * FBN + srow) * K_DIM + skh;

    f32x4 av[4];
    i32x4 wv[4];

    auto load_tiles = [&](int k0) {
        const f32x4* ap = (const f32x4*)(aptr + k0);
        const i32x4* wp = (const i32x4*)(wptr + k0);
        av[0] = ap[0]; av[1] = ap[1]; av[2] = ap[2]; av[3] = ap[3];
        wv[0] = wp[0]; wv[1] = wp[1]; wv[2] = wp[2]; wv[3] = wp[3];
    };

    auto stage = [&](int buf) {
        unsigned int apk[8], wpk[8];
        #pragma unroll
        for (int i = 0; i < 8; ++i) {
            apk[i] = pack2(av[(2*i) >> 2][(2*i) & 3], av[(2*i+1) >> 2][(2*i+1) & 3]);
            wpk[i] = pack2((float)wv[(2*i) >> 2][(2*i) & 3], (float)wv[(2*i+1) >> 2][(2*i+1) & 3]);
        }
        *(u32x4*)&Alds[buf][srow][skh]      = u32x4{apk[0], apk[1], apk[2], apk[3]};
        *(u32x4*)&Alds[buf][srow][skh + 8]  = u32x4{apk[4], apk[5], apk[6], apk[7]};
        *(u32x4*)&Blds2[buf][srow][skh]     = u32x4{wpk[0], wpk[1], wpk[2], wpk[3]};
        *(u32x4*)&Blds2[buf][srow][skh + 8] = u32x4{wpk[4], wpk[5], wpk[6], wpk[7]};
    };

    f32x4 acc[4][4];
    #pragma unroll
    for (int i = 0; i < 4; ++i)
        #pragma unroll
        for (int j = 0; j < 4; ++j)
            acc[i][j] = f32x4{0.f, 0.f, 0.f, 0.f};

    load_tiles(0);
    stage(0);
    __syncthreads();

    int cur = 0;
    for (int s = 0; s < FNSTEPS; ++s) {
        if (s + 1 < FNSTEPS) load_tiles((s + 1) * FBK);

        bf16x8 af[4], bfr[4];
        const int arow = wr * 64 + (lane & 15);
        const int brow = wc * 64 + (lane & 15);
        const int kb   = (lane >> 4) * 8;
        #pragma unroll
        for (int mf = 0; mf < 4; ++mf)
            af[mf] = *(const bf16x8*)&Alds[cur][arow + mf * 16][kb];
        #pragma unroll
        for (int nf = 0; nf < 4; ++nf)
            bfr[nf] = *(const bf16x8*)&Blds2[cur][brow + nf * 16][kb];

        #pragma unroll
        for (int mf = 0; mf < 4; ++mf)
            #pragma unroll
            for (int nf = 0; nf < 4; ++nf)
                acc[mf][nf] = __builtin_amdgcn_mfma_f32_16x16x32_bf16(
                    af[mf], bfr[nf], acc[mf][nf], 0, 0, 0);

        if (s + 1 < FNSTEPS) stage(cur ^ 1);
        __syncthreads();
        cur ^= 1;
    }

    #pragma unroll
    for (int nf = 0; nf < 4; ++nf) {
        const int n = nb * FBN + wc * 64 + nf * 16 + (lane & 15);
        const float sc = S[n];
        #pragma unroll
        for (int mf = 0; mf < 4; ++mf) {
            const int m0 = mb * FBM + wr * 64 + mf * 16 + ((lane >> 4) << 2);
            #pragma unroll
            for (int r = 0; r < 4; ++r)
                O[(size_t)(m0 + r) * N_DIM + n] = acc[mf][nf][r] * sc;
        }
    }
}

// ---------------- launch ----------------

extern "C" void kernel_launch(void* const* d_in, const int* in_sizes, int n_in,
                              void* d_out, int out_size, void* d_ws, size_t ws_size,
                              hipStream_t stream) {
    const float* X  = (const float*)d_in[0];
    const int*   Wq = (const int*)d_in[1];
    const float* S  = (const float*)d_in[2];
    float*       O  = (float*)d_out;

    const size_t XB_BYTES = (size_t)M_DIM * K_DIM * 2;
    const size_t WB_BYTES = (size_t)N_DIM * K_DIM * 2;

    if (ws_size >= XB_BYTES + WB_BYTES) {
        unsigned short* Xb = (unsigned short*)d_ws;
        unsigned short* Wb = (unsigned short*)((char*)d_ws + XB_BYTES);
        cvt_x_kernel<<<896, 256, 0, stream>>>(X, Xb);
        cvt_w_kernel<<<2048, 256, 0, stream>>>(Wq, Wb);
        lmhead_gemm_ad<<<NWG, 256, 0, stream>>>(Xb, Wb, S, O);
    } else {
        lmhead_gemm_conv<<<FNWG, 256, 0, stream>>>(X, Wq, S, O);
    }
}

// Round 9
// 707.825 us; speedup vs baseline: 11.3114x; 11.3114x over previous
//
#include <hip/hip_runtime.h>
#include <hip/hip_bf16.h>

// CustomLMHead: C[M,N] = X[M,K] @ (Wq[N,K] * scale[N])^T
// M=2048, N=151936, K=896.
//
// INT8 path: W is exactly int8; X is quantized per-row (absmax/127, RNE) so
// C = (Xq . Wq8) * Sx[m] * Sw[n] with EXACT int32 accumulation via
// mfma_i32_16x16x64_i8. GEMM structure = proven round-7 kernel byte-for-byte
// (128x128 tile, 4 waves, triple-buffered 48KiB LDS, T2 swizzle, counted
// vmcnt->barrier->read discipline, coalesced LDS epilogue), with BK=64 int8
// (same 64B/row, 16B/lane geometry as BK=32 bf16) -> NKT 28 -> 14.
// Fallback (small ws): bf16 reg-staging kernel with in-loop conversion.

#define M_DIM 2048
#define N_DIM 151936
#define K_DIM 896

#define BM 128
#define BN 128
#define BK 64                   // int8 K per tile (64 bytes/row slice)
#define NKT (K_DIM / BK)        // 14
#define MB_CNT (M_DIM / BM)     // 16
#define NB_CNT (N_DIM / BN)     // 1187 (exact)
#define NWG (MB_CNT * NB_CNT)   // 18992, divisible by 8

typedef __attribute__((ext_vector_type(8))) short bf16x8;
typedef __attribute__((ext_vector_type(4))) float f32x4;
typedef __attribute__((ext_vector_type(4))) int   i32x4;
typedef __attribute__((ext_vector_type(4))) unsigned int u32x4;
typedef __attribute__((ext_vector_type(2))) unsigned int u32x2;

static __device__ __forceinline__ unsigned short f2bf(float f) {
    unsigned int u = __builtin_bit_cast(unsigned int, f);
    u += 0x7FFFu + ((u >> 16) & 1u);
    return (unsigned short)(u >> 16);
}
static __device__ __forceinline__ unsigned int pack2(float lo, float hi) {
    return (unsigned int)f2bf(lo) | ((unsigned int)f2bf(hi) << 16);
}
static __device__ __forceinline__ void gload_lds16(const void* g, void* l) {
    __builtin_amdgcn_global_load_lds(
        (const __attribute__((address_space(1))) unsigned int*)g,
        (__attribute__((address_space(3))) unsigned int*)l, 16, 0, 0);
}

// ---------------- preconvert kernels ----------------

// per-row absmax quantization of X: one wave per row (896 = 64 lanes x 14)
__global__ void quant_x_kernel(const float* __restrict__ X,
                               signed char* __restrict__ Xq,
                               float* __restrict__ Sx) {
    const int row  = blockIdx.x * 4 + (threadIdx.x >> 6);
    const int lane = threadIdx.x & 63;
    const float* xr = X + (size_t)row * K_DIM;
    float v[14];
    float am = 0.f;
    #pragma unroll
    for (int i = 0; i < 14; ++i) {
        v[i] = xr[lane + i * 64];
        am = fmaxf(am, fabsf(v[i]));
    }
    #pragma unroll
    for (int off = 32; off > 0; off >>= 1)
        am = fmaxf(am, __shfl_xor(am, off));
    am = fmaxf(am, 1e-20f);
    const float inv = 127.f / am;
    if (lane == 0) Sx[row] = am / 127.f;
    signed char* qr = Xq + (size_t)row * K_DIM;
    #pragma unroll
    for (int i = 0; i < 14; ++i)
        qr[lane + i * 64] = (signed char)(int)rintf(v[i] * inv);
}

// W int32 (values in [-127,127]) -> int8 (truncate low byte is exact)
__global__ void cvt_w8_kernel(const int* __restrict__ Wq,
                              signed char* __restrict__ W8) {
    const long n8 = (long)N_DIM * K_DIM / 8;
    for (long i = (long)blockIdx.x * blockDim.x + threadIdx.x; i < n8;
         i += (long)gridDim.x * blockDim.x) {
        i32x4 a = ((const i32x4*)Wq)[2 * i];
        i32x4 b = ((const i32x4*)Wq)[2 * i + 1];
        unsigned int lo = (unsigned int)(a[0] & 0xff) |
                          ((unsigned int)(a[1] & 0xff) << 8) |
                          ((unsigned int)(a[2] & 0xff) << 16) |
                          ((unsigned int)(a[3] & 0xff) << 24);
        unsigned int hi = (unsigned int)(b[0] & 0xff) |
                          ((unsigned int)(b[1] & 0xff) << 8) |
                          ((unsigned int)(b[2] & 0xff) << 16) |
                          ((unsigned int)(b[3] & 0xff) << 24);
        u32x2 o; o[0] = lo; o[1] = hi;
        ((u32x2*)W8)[i] = o;
    }
}

// ---------------- 128x128 triple-buffered INT8 GEMM ----------------
// Identical sync structure to the PASSING round-7 kernel:
// Per tile t (buf t%3), 2 phases:
//   P0: READ A(q0)+B(buf t); stage tile t+2; BAR_A; MFMA q0; BAR_B.
//   P1: READ A(q1); vmcnt(4) [retires tile t+1, issued 2 phases ago];
//       BAR_A (publishes t+1); MFMA q1; BAR_B.
// Every barrier fenced with sched_barrier(0); BAR_B drains lgkmcnt(0).

#define SCHED0 __builtin_amdgcn_sched_barrier(0)
#define VMCNT(N) asm volatile("s_waitcnt vmcnt(" #N ")" ::: "memory")
#define LGKM0    asm volatile("s_waitcnt lgkmcnt(0)" ::: "memory")

__global__ __launch_bounds__(256, 3)
void lmhead_gemm_i8(const signed char* __restrict__ Xq,
                    const signed char* __restrict__ W8,
                    const float* __restrict__ Sw,
                    const float* __restrict__ Sx,
                    float* __restrict__ O)
{
    // [buf3][mat A=0/B=1][row 128][col 64 i8] = 48 KiB
    __shared__ signed char lds[3][2][BM][BK];

    const int tid  = threadIdx.x;
    const int lane = tid & 63;
    const int wave = tid >> 6;      // 0..3
    const int wr   = wave >> 1;     // 0..1
    const int wc   = wave & 1;      // 0..1

    // XCD-chunked bijective swizzle; mb fastest so the 16 m-blocks sharing
    // one 128-row W strip co-locate on one XCD's L2.
    const int bid = blockIdx.x;
    const int wg  = (bid & 7) * (NWG / 8) + (bid >> 3);
    const int mb  = wg % MB_CNT;
    const int nb  = wg / MB_CNT;

    // staging: per gload_lds, wave covers 16 rows of 64B; dest row =
    // base + (lane>>2), phys 16B-slot = lane&3. T2 swizzle phys =
    // logical ^ ((row>>1)&3) -> source slot = (lane&3) ^ ((lane>>3)&3).
    const int lslot = (lane & 3) ^ ((lane >> 3) & 3);
    const signed char* srcA0 =
        Xq + (size_t)(mb * BM + wave * 16 + (lane >> 2)) * K_DIM + lslot * 16;
    const signed char* srcA1 = srcA0 + (size_t)64 * K_DIM;
    const signed char* srcB0 =
        W8 + (size_t)(nb * BN + wave * 16 + (lane >> 2)) * K_DIM + lslot * 16;
    const signed char* srcB1 = srcB0 + (size_t)64 * K_DIM;

    auto stage = [&](int b3, int k0) {   // k0 in BYTES along K
        gload_lds16(srcA0 + k0, &lds[b3][0][wave * 16][0]);
        gload_lds16(srcA1 + k0, &lds[b3][0][64 + wave * 16][0]);
        gload_lds16(srcB0 + k0, &lds[b3][1][wave * 16][0]);
        gload_lds16(srcB1 + k0, &lds[b3][1][64 + wave * 16][0]);
    };

    // frag reads: row = R0 + (lane&15); lane holds 16 consecutive i8
    // (K-group = lane>>4); phys 16B-octet = (lane>>4) ^ ((lane>>1)&3).
    const int physoff   = ((lane >> 4) ^ ((lane >> 1) & 3)) * 16;   // bytes
    const int arow_base = wr * 64 + (lane & 15);
    const int brow_base = wc * 64 + (lane & 15);

    i32x4 acc[4][4];
    #pragma unroll
    for (int i = 0; i < 4; ++i)
        #pragma unroll
        for (int j = 0; j < 4; ++j)
            acc[i][j] = i32x4{0, 0, 0, 0};

    // prologue: stage tiles 0,1; full drain; publish
    stage(0, 0);
    stage(1, BK);
    SCHED0;
    VMCNT(0);
    SCHED0;
    __builtin_amdgcn_s_barrier();
    SCHED0;

    i32x4 af[2], bfr[4];

#define READ_A(B3, Q) do { \
    _Pragma("unroll") \
    for (int mf = 0; mf < 2; ++mf) \
        af[mf] = *(const i32x4*)&lds[B3][0][arow_base + (Q)*32 + mf*16][physoff]; \
} while (0)
#define READ_B(B3) do { \
    _Pragma("unroll") \
    for (int nf = 0; nf < 4; ++nf) \
        bfr[nf] = *(const i32x4*)&lds[B3][1][brow_base + nf*16][physoff]; \
} while (0)
#define MFMA_Q(Q) do { \
    __builtin_amdgcn_s_setprio(1); \
    _Pragma("unroll") \
    for (int mf = 0; mf < 2; ++mf) { \
        _Pragma("unroll") \
        for (int nf = 0; nf < 4; ++nf) \
            acc[(Q)*2 + mf][nf] = __builtin_amdgcn_mfma_i32_16x16x64_i8( \
                af[mf], bfr[nf], acc[(Q)*2 + mf][nf], 0, 0, 0); \
    } \
    __builtin_amdgcn_s_setprio(0); \
} while (0)
#define BAR_A() do { SCHED0; __builtin_amdgcn_s_barrier(); SCHED0; } while (0)
#define BAR_B() do { SCHED0; LGKM0; SCHED0; __builtin_amdgcn_s_barrier(); SCHED0; } while (0)

    for (int t = 0; t < NKT - 2; ++t) {   // t = 0..11
        const int cur = t % 3;
        // P0
        READ_A(cur, 0); READ_B(cur);
        stage((t + 2) % 3, (t + 2) * BK);
        BAR_A();
        MFMA_Q(0);
        BAR_B();
        // P1
        READ_A(cur, 1);
        SCHED0;
        VMCNT(4);       // retires tile t+1's 4 loads (issued at (t-1).P0)
        BAR_A();        // publishes tile t+1
        MFMA_Q(1);
        BAR_B();
    }

    // peel t = NKT-2 = 12: no staging; drain tile NKT-1's batch
    {
        const int cur = (NKT - 2) % 3;   // 0
        READ_A(cur, 0); READ_B(cur);
        BAR_A();
        MFMA_Q(0);
        BAR_B();
        READ_A(cur, 1);
        SCHED0;
        VMCNT(0);       // tile NKT-1's batch, issued 2 phases ago
        BAR_A();
        MFMA_Q(1);
        BAR_B();
    }
    // peel t = NKT-1 = 13
    {
        const int cur = (NKT - 1) % 3;   // 1
        READ_A(cur, 0); READ_B(cur);
        BAR_A();
        MFMA_Q(0);
        BAR_B();
        READ_A(cur, 1);
        BAR_A();
        MFMA_Q(1);
    }

#undef READ_A
#undef READ_B
#undef MFMA_Q
#undef BAR_A
#undef BAR_B

    // ---- LDS-coalesced epilogue (proven round-7 structure) ----
    // Reuse LDS as float[64][128] (32 KiB), 2 passes (row halves).
    // Writes: (float)acc * Sw[n], XOR-swizzled pcol = col ^ (qw<<4).
    // Reads: f32x4 * Sx[row] -> full 128B-line global row stores.
    __syncthreads();   // all K-loop work fully drained

    float* lf = (float*)&lds[0][0][0][0];
    const int qw = lane >> 4;     // 0..3
    const int li = lane & 15;

    float scn[4];
    #pragma unroll
    for (int nf = 0; nf < 4; ++nf)
        scn[nf] = Sw[nb * BN + wc * 64 + nf * 16 + li];

    #pragma unroll
    for (int p = 0; p < 2; ++p) {
        if (p) __syncthreads();   // pass-0 reads before pass-1 writes
        if (wr == p) {
            #pragma unroll
            for (int a = 0; a < 4; ++a) {
                #pragma unroll
                for (int nf = 0; nf < 4; ++nf) {
                    #pragma unroll
                    for (int r = 0; r < 4; ++r) {
                        const int lr   = a * 16 + qw * 4 + r;
                        const int col  = wc * 64 + nf * 16 + li;
                        const int pcol = col ^ (qw << 4);
                        lf[lr * 128 + pcol] = (float)acc[a][nf][r] * scn[nf];
                    }
                }
            }
        }
        __syncthreads();
        #pragma unroll
        for (int i = 0; i < 8; ++i) {
            const int row = wave * 16 + i * 2 + (lane >> 5);
            const int q   = (row >> 2) & 3;
            const int pch = (lane & 31) ^ (q << 2);
            f32x4 v = *(const f32x4*)&lf[row * 128 + pch * 4];
            const size_t grow = (size_t)(mb * BM + p * 64 + row);
            const float sxr = Sx[grow];
            v *= sxr;
            const size_t gcol = (size_t)(nb * BN + (lane & 31) * 4);
            *(f32x4*)&O[grow * N_DIM + gcol] = v;
        }
    }
}

// ---------------- fallback: bf16 reg staging + in-loop convert ----------------

#define FBM 128
#define FBN 128
#define FBK 32
#define FNSTEPS (K_DIM / FBK)
#define FMB (M_DIM / FBM)
#define FNB (N_DIM / FBN)
#define FNWG (FMB * FNB)

__global__ __launch_bounds__(256, 2)
void lmhead_gemm_conv(const float* __restrict__ X,
                      const int* __restrict__ Wq,
                      const float* __restrict__ S,
                      float* __restrict__ O)
{
    __shared__ unsigned short Alds[2][FBM][FBK];
    __shared__ unsigned short Blds2[2][FBN][FBK];

    const int tid  = threadIdx.x;
    const int lane = tid & 63;
    const int wave = tid >> 6;
    const int wr   = wave >> 1;
    const int wc   = wave & 1;

    const int bid = blockIdx.x;
    const int wg  = (bid & 7) * (FNWG / 8) + (bid >> 3);
    const int mb  = wg % FMB;
    const int nb  = wg / FMB;

    const int srow = tid >> 1;
    const int skh  = (tid & 1) * 16;

    const float* aptr = X  + (size_t)(mb * FBM + srow) * K_DIM + skh;
    const int*   wptr = Wq + (size_t)(nb * FBN + srow) * K_DIM + skh;

    f32x4 av[4];
    i32x4 wv[4];

    auto load_tiles = [&](int k0) {
        const f32x4* ap = (const f32x4*)(aptr + k0);
        const i32x4* wp = (const i32x4*)(wptr + k0);
        av[0] = ap[0]; av[1] = ap[1]; av[2] = ap[2]; av[3] = ap[3];
        wv[0] = wp[0]; wv[1] = wp[1]; wv[2] = wp[2]; wv[3] = wp[3];
    };

    auto stage = [&](int buf) {
        unsigned int apk[8], wpk[8];
        #pragma unroll
        for (int i = 0; i < 8; ++i) {
            apk[i] = pack2(av[(2*i) >> 2][(2*i) & 3], av[(2*i+1) >> 2][(2*i+1) & 3]);
            wpk[i] = pack2((float)wv[(2*i) >> 2][(2*i) & 3], (float)wv[(2*i+1) >> 2][(2*i+1) & 3]);
        }
        *(u32x4*)&Alds[buf][srow][skh]      = u32x4{apk[0], apk[1], apk[2], apk[3]};
        *(u32x4*)&Alds[buf][srow][skh + 8]  = u32x4{apk[4], apk[5], apk[6], apk[7]};
        *(u32x4*)&Blds2[buf][srow][skh]     = u32x4{wpk[0], wpk[1], wpk[2], wpk[3]};
        *(u32x4*)&Blds2[buf][srow][skh + 8] = u32x4{wpk[4], wpk[5], wpk[6], wpk[7]};
    };

    f32x4 acc[4][4];
    #pragma unroll
    for (int i = 0; i < 4; ++i)
        #pragma unroll
        for (int j = 0; j < 4; ++j)
            acc[i][j] = f32x4{0.f, 0.f, 0.f, 0.f};

    load_tiles(0);
    stage(0);
    __syncthreads();

    int cur = 0;
    for (int s = 0; s < FNSTEPS; ++s) {
        if (s + 1 < FNSTEPS) load_tiles((s + 1) * FBK);

        bf16x8 af[4], bfr[4];
        const int arow = wr * 64 + (lane & 15);
        const int brow = wc * 64 + (lane & 15);
        const int kb   = (lane >> 4) * 8;
        #pragma unroll
        for (int mf = 0; mf < 4; ++mf)
            af[mf] = *(const bf16x8*)&Alds[cur][arow + mf * 16][kb];
        #pragma unroll
        for (int nf = 0; nf < 4; ++nf)
            bfr[nf] = *(const bf16x8*)&Blds2[cur][brow + nf * 16][kb];

        #pragma unroll
        for (int mf = 0; mf < 4; ++mf)
            #pragma unroll
            for (int nf = 0; nf < 4; ++nf)
                acc[mf][nf] = __builtin_amdgcn_mfma_f32_16x16x32_bf16(
                    af[mf], bfr[nf], acc[mf][nf], 0, 0, 0);

        if (s + 1 < FNSTEPS) stage(cur ^ 1);
        __syncthreads();
        cur ^= 1;
    }

    #pragma unroll
    for (int nf = 0; nf < 4; ++nf) {
        const int n = nb * FBN + wc * 64 + nf * 16 + (lane & 15);
        const float sc = S[n];
        #pragma unroll
        for (int mf = 0; mf < 4; ++mf) {
            const int m0 = mb * FBM + wr * 64 + mf * 16 + ((lane >> 4) << 2);
            #pragma unroll
            for (int r = 0; r < 4; ++r)
                O[(size_t)(m0 + r) * N_DIM + n] = acc[mf][nf][r] * sc;
        }
    }
}

// ---------------- launch ----------------

extern "C" void kernel_launch(void* const* d_in, const int* in_sizes, int n_in,
                              void* d_out, int out_size, void* d_ws, size_t ws_size,
                              hipStream_t stream) {
    const float* X  = (const float*)d_in[0];
    const int*   Wq = (const int*)d_in[1];
    const float* S  = (const float*)d_in[2];
    float*       O  = (float*)d_out;

    const size_t XQ_BYTES = (size_t)M_DIM * K_DIM;            // 1,835,008
    const size_t SX_BYTES = (size_t)M_DIM * sizeof(float);    // 8,192
    const size_t W8_BYTES = (size_t)N_DIM * K_DIM;            // 136,134,656

    if (ws_size >= XQ_BYTES + SX_BYTES + W8_BYTES) {
        signed char* xq = (signed char*)d_ws;
        float*       sx = (float*)((char*)d_ws + XQ_BYTES);
        signed char* w8 = (signed char*)((char*)d_ws + XQ_BYTES + SX_BYTES);
        quant_x_kernel<<<M_DIM / 4, 256, 0, stream>>>(X, xq, sx);
        cvt_w8_kernel<<<2048, 256, 0, stream>>>(Wq, w8);
        lmhead_gemm_i8<<<NWG, 256, 0, stream>>>(xq, w8, S, sx, O);
    } else {
        lmhead_gemm_conv<<<FNWG, 256, 0, stream>>>(X, Wq, S, O);
    }
}

// Round 10
// 701.229 us; speedup vs baseline: 11.4178x; 1.0094x over previous
//
#include <hip/hip_runtime.h>
#include <hip/hip_bf16.h>

// CustomLMHead: C[M,N] = X[M,K] @ (Wq[N,K] * scale[N])^T
// M=2048, N=151936, K=896.
//
// INT8 path: W is exactly int8; X quantized per-row (absmax/127, RNE);
// C = (Xq . Wq8) * Sx[m] * Sw[n], exact int32 accumulation via
// mfma_i32_16x16x64_i8. 128x128 tile, 4 waves, triple-buffered 48 KiB LDS,
// T2 swizzle, coalesced LDS epilogue (all proven round-9). THIS ROUND:
// single-barrier K-loop — per tile {8 ds_read; stage(t+2); vmcnt(4);
// lgkmcnt(0); s_barrier; 16 MFMA} instead of the 2-phase/4-barrier body.
//   RAW: stage(t+1) issued at t-1; vmcnt(4) at t retires it; barrier at t
//        publishes; consumed at t+1 after that barrier.
//   WAR: buf[t%3] overwritten by stage issued at t+1 (after t's barrier);
//        my buf[t] reads drained by lgkmcnt(0) before t's barrier.
// Fallback (small ws): bf16 reg-staging kernel with in-loop conversion.

#define M_DIM 2048
#define N_DIM 151936
#define K_DIM 896

#define BM 128
#define BN 128
#define BK 64                   // int8 K per tile (64 bytes/row slice)
#define NKT (K_DIM / BK)        // 14
#define MB_CNT (M_DIM / BM)     // 16
#define NB_CNT (N_DIM / BN)     // 1187 (exact)
#define NWG (MB_CNT * NB_CNT)   // 18992, divisible by 8

typedef __attribute__((ext_vector_type(8))) short bf16x8;
typedef __attribute__((ext_vector_type(4))) float f32x4;
typedef __attribute__((ext_vector_type(4))) int   i32x4;
typedef __attribute__((ext_vector_type(4))) unsigned int u32x4;
typedef __attribute__((ext_vector_type(2))) unsigned int u32x2;

static __device__ __forceinline__ unsigned short f2bf(float f) {
    unsigned int u = __builtin_bit_cast(unsigned int, f);
    u += 0x7FFFu + ((u >> 16) & 1u);
    return (unsigned short)(u >> 16);
}
static __device__ __forceinline__ unsigned int pack2(float lo, float hi) {
    return (unsigned int)f2bf(lo) | ((unsigned int)f2bf(hi) << 16);
}
static __device__ __forceinline__ void gload_lds16(const void* g, void* l) {
    __builtin_amdgcn_global_load_lds(
        (const __attribute__((address_space(1))) unsigned int*)g,
        (__attribute__((address_space(3))) unsigned int*)l, 16, 0, 0);
}

// ---------------- preconvert kernels (proven round-9) ----------------

// per-row absmax quantization of X: one wave per row (896 = 64 lanes x 14)
__global__ void quant_x_kernel(const float* __restrict__ X,
                               signed char* __restrict__ Xq,
                               float* __restrict__ Sx) {
    const int row  = blockIdx.x * 4 + (threadIdx.x >> 6);
    const int lane = threadIdx.x & 63;
    const float* xr = X + (size_t)row * K_DIM;
    float v[14];
    float am = 0.f;
    #pragma unroll
    for (int i = 0; i < 14; ++i) {
        v[i] = xr[lane + i * 64];
        am = fmaxf(am, fabsf(v[i]));
    }
    #pragma unroll
    for (int off = 32; off > 0; off >>= 1)
        am = fmaxf(am, __shfl_xor(am, off));
    am = fmaxf(am, 1e-20f);
    const float inv = 127.f / am;
    if (lane == 0) Sx[row] = am / 127.f;
    signed char* qr = Xq + (size_t)row * K_DIM;
    #pragma unroll
    for (int i = 0; i < 14; ++i)
        qr[lane + i * 64] = (signed char)(int)rintf(v[i] * inv);
}

// W int32 (values in [-127,127]) -> int8 (truncate low byte is exact)
__global__ void cvt_w8_kernel(const int* __restrict__ Wq,
                              signed char* __restrict__ W8) {
    const long n8 = (long)N_DIM * K_DIM / 8;
    for (long i = (long)blockIdx.x * blockDim.x + threadIdx.x; i < n8;
         i += (long)gridDim.x * blockDim.x) {
        i32x4 a = ((const i32x4*)Wq)[2 * i];
        i32x4 b = ((const i32x4*)Wq)[2 * i + 1];
        unsigned int lo = (unsigned int)(a[0] & 0xff) |
                          ((unsigned int)(a[1] & 0xff) << 8) |
                          ((unsigned int)(a[2] & 0xff) << 16) |
                          ((unsigned int)(a[3] & 0xff) << 24);
        unsigned int hi = (unsigned int)(b[0] & 0xff) |
                          ((unsigned int)(b[1] & 0xff) << 8) |
                          ((unsigned int)(b[2] & 0xff) << 16) |
                          ((unsigned int)(b[3] & 0xff) << 24);
        u32x2 o; o[0] = lo; o[1] = hi;
        ((u32x2*)W8)[i] = o;
    }
}

// ---------------- 128x128 triple-buffered INT8 GEMM, 1 barrier/tile ----------------

#define SCHED0 __builtin_amdgcn_sched_barrier(0)
#define VMCNT(N) asm volatile("s_waitcnt vmcnt(" #N ")" ::: "memory")
#define LGKM0    asm volatile("s_waitcnt lgkmcnt(0)" ::: "memory")

__global__ __launch_bounds__(256, 3)
void lmhead_gemm_i8(const signed char* __restrict__ Xq,
                    const signed char* __restrict__ W8,
                    const float* __restrict__ Sw,
                    const float* __restrict__ Sx,
                    float* __restrict__ O)
{
    // [buf3][mat A=0/B=1][row 128][col 64 i8] = 48 KiB
    __shared__ signed char lds[3][2][BM][BK];

    const int tid  = threadIdx.x;
    const int lane = tid & 63;
    const int wave = tid >> 6;      // 0..3
    const int wr   = wave >> 1;     // 0..1
    const int wc   = wave & 1;      // 0..1

    // XCD-chunked bijective swizzle; mb fastest so the 16 m-blocks sharing
    // one 128-row W strip co-locate on one XCD's L2.
    const int bid = blockIdx.x;
    const int wg  = (bid & 7) * (NWG / 8) + (bid >> 3);
    const int mb  = wg % MB_CNT;
    const int nb  = wg / MB_CNT;

    // staging: per gload_lds, wave covers 16 rows of 64B; dest row =
    // base + (lane>>2), phys 16B-slot = lane&3. T2 swizzle phys =
    // logical ^ ((row>>1)&3) -> source slot = (lane&3) ^ ((lane>>3)&3).
    const int lslot = (lane & 3) ^ ((lane >> 3) & 3);
    const signed char* srcA0 =
        Xq + (size_t)(mb * BM + wave * 16 + (lane >> 2)) * K_DIM + lslot * 16;
    const signed char* srcA1 = srcA0 + (size_t)64 * K_DIM;
    const signed char* srcB0 =
        W8 + (size_t)(nb * BN + wave * 16 + (lane >> 2)) * K_DIM + lslot * 16;
    const signed char* srcB1 = srcB0 + (size_t)64 * K_DIM;

    auto stage = [&](int b3, int k0) {   // k0 in BYTES along K
        gload_lds16(srcA0 + k0, &lds[b3][0][wave * 16][0]);
        gload_lds16(srcA1 + k0, &lds[b3][0][64 + wave * 16][0]);
        gload_lds16(srcB0 + k0, &lds[b3][1][wave * 16][0]);
        gload_lds16(srcB1 + k0, &lds[b3][1][64 + wave * 16][0]);
    };

    // frag reads: row = R0 + (lane&15); lane holds 16 consecutive i8
    // (K-group = lane>>4); phys 16B-octet = (lane>>4) ^ ((lane>>1)&3).
    const int physoff   = ((lane >> 4) ^ ((lane >> 1) & 3)) * 16;   // bytes
    const int arow_base = wr * 64 + (lane & 15);
    const int brow_base = wc * 64 + (lane & 15);

    i32x4 acc[4][4];
    #pragma unroll
    for (int i = 0; i < 4; ++i)
        #pragma unroll
        for (int j = 0; j < 4; ++j)
            acc[i][j] = i32x4{0, 0, 0, 0};

    // prologue: stage tiles 0,1; retire tile 0 (oldest 4); publish
    stage(0, 0);
    stage(1, BK);
    SCHED0;
    VMCNT(4);
    SCHED0;
    __builtin_amdgcn_s_barrier();
    SCHED0;

    i32x4 af[4], bfr[4];

#define READ_AB(B3) do { \
    _Pragma("unroll") \
    for (int mf = 0; mf < 4; ++mf) \
        af[mf] = *(const i32x4*)&lds[B3][0][arow_base + mf * 16][physoff]; \
    _Pragma("unroll") \
    for (int nf = 0; nf < 4; ++nf) \
        bfr[nf] = *(const i32x4*)&lds[B3][1][brow_base + nf * 16][physoff]; \
} while (0)
#define MFMA16() do { \
    __builtin_amdgcn_s_setprio(1); \
    _Pragma("unroll") \
    for (int mf = 0; mf < 4; ++mf) { \
        _Pragma("unroll") \
        for (int nf = 0; nf < 4; ++nf) \
            acc[mf][nf] = __builtin_amdgcn_mfma_i32_16x16x64_i8( \
                af[mf], bfr[nf], acc[mf][nf], 0, 0, 0); \
    } \
    __builtin_amdgcn_s_setprio(0); \
} while (0)

    for (int t = 0; t < NKT - 2; ++t) {   // t = 0..11
        const int cur = t % 3;
        READ_AB(cur);
        stage((t + 2) % 3, (t + 2) * BK);
        SCHED0;
        VMCNT(4);       // retires stage(t+1), issued at tile t-1
        LGKM0;          // my buf[t] reads drained before the barrier
        SCHED0;
        __builtin_amdgcn_s_barrier();   // publishes tile t+1; gates WAR
        SCHED0;
        MFMA16();
    }

    // t = NKT-2 = 12: no stage; drain tile NKT-1's batch
    {
        READ_AB((NKT - 2) % 3);
        SCHED0;
        VMCNT(0);
        LGKM0;
        SCHED0;
        __builtin_amdgcn_s_barrier();
        SCHED0;
        MFMA16();
    }
    // t = NKT-1 = 13: reads only (published at previous barrier)
    {
        READ_AB((NKT - 1) % 3);
        SCHED0;
        LGKM0;
        SCHED0;
        MFMA16();
    }

#undef READ_AB
#undef MFMA16

    // ---- LDS-coalesced epilogue (proven round-9 structure) ----
    // Reuse LDS as float[64][128] (32 KiB), 2 passes (row halves).
    // Writes: (float)acc * Sw[n], XOR-swizzled pcol = col ^ (qw<<4).
    // Reads: f32x4 * Sx[row] -> full 128B-line global row stores.
    __syncthreads();   // all K-loop work fully drained

    float* lf = (float*)&lds[0][0][0][0];
    const int qw = lane >> 4;     // 0..3
    const int li = lane & 15;

    float scn[4];
    #pragma unroll
    for (int nf = 0; nf < 4; ++nf)
        scn[nf] = Sw[nb * BN + wc * 64 + nf * 16 + li];

    #pragma unroll
    for (int p = 0; p < 2; ++p) {
        if (p) __syncthreads();   // pass-0 reads before pass-1 writes
        if (wr == p) {
            #pragma unroll
            for (int a = 0; a < 4; ++a) {
                #pragma unroll
                for (int nf = 0; nf < 4; ++nf) {
                    #pragma unroll
                    for (int r = 0; r < 4; ++r) {
                        const int lr   = a * 16 + qw * 4 + r;
                        const int col  = wc * 64 + nf * 16 + li;
                        const int pcol = col ^ (qw << 4);
                        lf[lr * 128 + pcol] = (float)acc[a][nf][r] * scn[nf];
                    }
                }
            }
        }
        __syncthreads();
        #pragma unroll
        for (int i = 0; i < 8; ++i) {
            const int row = wave * 16 + i * 2 + (lane >> 5);
            const int q   = (row >> 2) & 3;
            const int pch = (lane & 31) ^ (q << 2);
            f32x4 v = *(const f32x4*)&lf[row * 128 + pch * 4];
            const size_t grow = (size_t)(mb * BM + p * 64 + row);
            const float sxr = Sx[grow];
            v *= sxr;
            const size_t gcol = (size_t)(nb * BN + (lane & 31) * 4);
            *(f32x4*)&O[grow * N_DIM + gcol] = v;
        }
    }
}

// ---------------- fallback: bf16 reg staging + in-loop convert ----------------

#define FBM 128
#define FBN 128
#define FBK 32
#define FNSTEPS (K_DIM / FBK)
#define FMB (M_DIM / FBM)
#define FNB (N_DIM / FBN)
#define FNWG (FMB * FNB)

__global__ __launch_bounds__(256, 2)
void lmhead_gemm_conv(const float* __restrict__ X,
                      const int* __restrict__ Wq,
                      const float* __restrict__ S,
                      float* __restrict__ O)
{
    __shared__ unsigned short Alds[2][FBM][FBK];
    __shared__ unsigned short Blds2[2][FBN][FBK];

    const int tid  = threadIdx.x;
    const int lane = tid & 63;
    const int wave = tid >> 6;
    const int wr   = wave >> 1;
    const int wc   = wave & 1;

    const int bid = blockIdx.x;
    const int wg  = (bid & 7) * (FNWG / 8) + (bid >> 3);
    const int mb  = wg % FMB;
    const int nb  = wg / FMB;

    const int srow = tid >> 1;
    const int skh  = (tid & 1) * 16;

    const float* aptr = X  + (size_t)(mb * FBM + srow) * K_DIM + skh;
    const int*   wptr = Wq + (size_t)(nb * FBN + srow) * K_DIM + skh;

    f32x4 av[4];
    i32x4 wv[4];

    auto load_tiles = [&](int k0) {
        const f32x4* ap = (const f32x4*)(aptr + k0);
        const i32x4* wp = (const i32x4*)(wptr + k0);
        av[0] = ap[0]; av[1] = ap[1]; av[2] = ap[2]; av[3] = ap[3];
        wv[0] = wp[0]; wv[1] = wp[1]; wv[2] = wp[2]; wv[3] = wp[3];
    };

    auto stage = [&](int buf) {
        unsigned int apk[8], wpk[8];
        #pragma unroll
        for (int i = 0; i < 8; ++i) {
            apk[i] = pack2(av[(2*i) >> 2][(2*i) & 3], av[(2*i+1) >> 2][(2*i+1) & 3]);
            wpk[i] = pack2((float)wv[(2*i) >> 2][(2*i) & 3], (float)wv[(2*i+1) >> 2][(2*i+1) & 3]);
        }
        *(u32x4*)&Alds[buf][srow][skh]      = u32x4{apk[0], apk[1], apk[2], apk[3]};
        *(u32x4*)&Alds[buf][srow][skh + 8]  = u32x4{apk[4], apk[5], apk[6], apk[7]};
        *(u32x4*)&Blds2[buf][srow][skh]     = u32x4{wpk[0], wpk[1], wpk[2], wpk[3]};
        *(u32x4*)&Blds2[buf][srow][skh + 8] = u32x4{wpk[4], wpk[5], wpk[6], wpk[7]};
    };

    f32x4 acc[4][4];
    #pragma unroll
    for (int i = 0; i < 4; ++i)
        #pragma unroll
        for (int j = 0; j < 4; ++j)
            acc[i][j] = f32x4{0.f, 0.f, 0.f, 0.f};

    load_tiles(0);
    stage(0);
    __syncthreads();

    int cur = 0;
    for (int s = 0; s < FNSTEPS; ++s) {
        if (s + 1 < FNSTEPS) load_tiles((s + 1) * FBK);

        bf16x8 af[4], bfr[4];
        const int arow = wr * 64 + (lane & 15);
        const int brow = wc * 64 + (lane & 15);
        const int kb   = (lane >> 4) * 8;
        #pragma unroll
        for (int mf = 0; mf < 4; ++mf)
            af[mf] = *(const bf16x8*)&Alds[cur][arow + mf * 16][kb];
        #pragma unroll
        for (int nf = 0; nf < 4; ++nf)
            bfr[nf] = *(const bf16x8*)&Blds2[cur][brow + nf * 16][kb];

        #pragma unroll
        for (int mf = 0; mf < 4; ++mf)
            #pragma unroll
            for (int nf = 0; nf < 4; ++nf)
                acc[mf][nf] = __builtin_amdgcn_mfma_f32_16x16x32_bf16(
                    af[mf], bfr[nf], acc[mf][nf], 0, 0, 0);

        if (s + 1 < FNSTEPS) stage(cur ^ 1);
        __syncthreads();
        cur ^= 1;
    }

    #pragma unroll
    for (int nf = 0; nf < 4; ++nf) {
        const int n = nb * FBN + wc * 64 + nf * 16 + (lane & 15);
        const float sc = S[n];
        #pragma unroll
        for (int mf = 0; mf < 4; ++mf) {
            const int m0 = mb * FBM + wr * 64 + mf * 16 + ((lane >> 4) << 2);
            #pragma unroll
            for (int r = 0; r < 4; ++r)
                O[(size_t)(m0 + r) * N_DIM + n] = acc[mf][nf][r] * sc;
        }
    }
}

// ---------------- launch ----------------

extern "C" void kernel_launch(void* const* d_in, const int* in_sizes, int n_in,
                              void* d_out, int out_size, void* d_ws, size_t ws_size,
                              hipStream_t stream) {
    const float* X  = (const float*)d_in[0];
    const int*   Wq = (const int*)d_in[1];
    const float* S  = (const float*)d_in[2];
    float*       O  = (float*)d_out;

    const size_t XQ_BYTES = (size_t)M_DIM * K_DIM;            // 1,835,008
    const size_t SX_BYTES = (size_t)M_DIM * sizeof(float);    // 8,192
    const size_t W8_BYTES = (size_t)N_DIM * K_DIM;            // 136,134,656

    if (ws_size >= XQ_BYTES + SX_BYTES + W8_BYTES) {
        signed char* xq = (signed char*)d_ws;
        float*       sx = (float*)((char*)d_ws + XQ_BYTES);
        signed char* w8 = (signed char*)((char*)d_ws + XQ_BYTES + SX_BYTES);
        quant_x_kernel<<<M_DIM / 4, 256, 0, stream>>>(X, xq, sx);
        cvt_w8_kernel<<<2048, 256, 0, stream>>>(Wq, w8);
        lmhead_gemm_i8<<<NWG, 256, 0, stream>>>(xq, w8, S, sx, O);
    } else {
        lmhead_gemm_conv<<<FNWG, 256, 0, stream>>>(X, Wq, S, O);
    }
}

// Round 11
// 686.180 us; speedup vs baseline: 11.6682x; 1.0219x over previous
//
#include <hip/hip_runtime.h>
#include <hip/hip_bf16.h>

// CustomLMHead: C[M,N] = X[M,K] @ (Wq[N,K] * scale[N])^T
// M=2048, N=151936, K=896.
//
// INT8 path: W is exactly int8; X quantized per-row (absmax/127, RNE);
// C = (Xq . Wq8) * Sx[m] * Sw[n], exact int32 accumulation via
// mfma_i32_16x16x64_i8. THIS ROUND: 256x128 tile (2x the M per block),
// 4 waves of 128x64 each (acc 8x4 i32x4), triple-buffered 72 KiB LDS,
// 2 blocks/CU, single-barrier K-loop with counted vmcnt (lookahead 2),
// T2 swizzle, coalesced LDS epilogue (4 passes of float[64][128]).
//   RAW: stage(t+1) issued at t-1; vmcnt(6) at t retires it; barrier at t
//        publishes; consumed at t+1 after that barrier.
//   WAR: buf[t%3] overwritten by stage issued at t+1 (after t's barrier);
//        my buf[t] reads drained by lgkmcnt(0) before t's barrier.
// Fallback (small ws): bf16 reg-staging kernel with in-loop conversion.

#define M_DIM 2048
#define N_DIM 151936
#define K_DIM 896

#define BM 256
#define BN 128
#define BK 64                   // int8 K per tile (64 bytes/row slice)
#define NKT (K_DIM / BK)        // 14
#define MB_CNT (M_DIM / BM)     // 8
#define NB_CNT (N_DIM / BN)     // 1187 (exact)
#define NWG (MB_CNT * NB_CNT)   // 9496, divisible by 8

typedef __attribute__((ext_vector_type(8))) short bf16x8;
typedef __attribute__((ext_vector_type(4))) float f32x4;
typedef __attribute__((ext_vector_type(4))) int   i32x4;
typedef __attribute__((ext_vector_type(4))) unsigned int u32x4;
typedef __attribute__((ext_vector_type(2))) unsigned int u32x2;

static __device__ __forceinline__ unsigned short f2bf(float f) {
    unsigned int u = __builtin_bit_cast(unsigned int, f);
    u += 0x7FFFu + ((u >> 16) & 1u);
    return (unsigned short)(u >> 16);
}
static __device__ __forceinline__ unsigned int pack2(float lo, float hi) {
    return (unsigned int)f2bf(lo) | ((unsigned int)f2bf(hi) << 16);
}
static __device__ __forceinline__ void gload_lds16(const void* g, void* l) {
    __builtin_amdgcn_global_load_lds(
        (const __attribute__((address_space(1))) unsigned int*)g,
        (__attribute__((address_space(3))) unsigned int*)l, 16, 0, 0);
}

// ---------------- preconvert kernels (proven round-9/10) ----------------

// per-row absmax quantization of X: one wave per row (896 = 64 lanes x 14)
__global__ void quant_x_kernel(const float* __restrict__ X,
                               signed char* __restrict__ Xq,
                               float* __restrict__ Sx) {
    const int row  = blockIdx.x * 4 + (threadIdx.x >> 6);
    const int lane = threadIdx.x & 63;
    const float* xr = X + (size_t)row * K_DIM;
    float v[14];
    float am = 0.f;
    #pragma unroll
    for (int i = 0; i < 14; ++i) {
        v[i] = xr[lane + i * 64];
        am = fmaxf(am, fabsf(v[i]));
    }
    #pragma unroll
    for (int off = 32; off > 0; off >>= 1)
        am = fmaxf(am, __shfl_xor(am, off));
    am = fmaxf(am, 1e-20f);
    const float inv = 127.f / am;
    if (lane == 0) Sx[row] = am / 127.f;
    signed char* qr = Xq + (size_t)row * K_DIM;
    #pragma unroll
    for (int i = 0; i < 14; ++i)
        qr[lane + i * 64] = (signed char)(int)rintf(v[i] * inv);
}

// W int32 (values in [-127,127]) -> int8 (truncate low byte is exact)
__global__ void cvt_w8_kernel(const int* __restrict__ Wq,
                              signed char* __restrict__ W8) {
    const long n8 = (long)N_DIM * K_DIM / 8;
    for (long i = (long)blockIdx.x * blockDim.x + threadIdx.x; i < n8;
         i += (long)gridDim.x * blockDim.x) {
        i32x4 a = ((const i32x4*)Wq)[2 * i];
        i32x4 b = ((const i32x4*)Wq)[2 * i + 1];
        unsigned int lo = (unsigned int)(a[0] & 0xff) |
                          ((unsigned int)(a[1] & 0xff) << 8) |
                          ((unsigned int)(a[2] & 0xff) << 16) |
                          ((unsigned int)(a[3] & 0xff) << 24);
        unsigned int hi = (unsigned int)(b[0] & 0xff) |
                          ((unsigned int)(b[1] & 0xff) << 8) |
                          ((unsigned int)(b[2] & 0xff) << 16) |
                          ((unsigned int)(b[3] & 0xff) << 24);
        u32x2 o; o[0] = lo; o[1] = hi;
        ((u32x2*)W8)[i] = o;
    }
}

// ---------------- 256x128 triple-buffered INT8 GEMM, 1 barrier/tile ----------------

#define SCHED0 __builtin_amdgcn_sched_barrier(0)
#define VMCNT(N) asm volatile("s_waitcnt vmcnt(" #N ")" ::: "memory")
#define LGKM0    asm volatile("s_waitcnt lgkmcnt(0)" ::: "memory")

__global__ __launch_bounds__(256, 2)
void lmhead_gemm_i8(const signed char* __restrict__ Xq,
                    const signed char* __restrict__ W8,
                    const float* __restrict__ Sw,
                    const float* __restrict__ Sx,
                    float* __restrict__ O)
{
    // A: 3 x 256x64 i8 = 48 KiB, B: 3 x 128x64 i8 = 24 KiB -> 72 KiB total
    __shared__ signed char ldsA[3][BM][BK];
    __shared__ signed char ldsB[3][BN][BK];

    const int tid  = threadIdx.x;
    const int lane = tid & 63;
    const int wave = tid >> 6;      // 0..3
    const int wr   = wave >> 1;     // 0..1 (row half: 128 rows each)
    const int wc   = wave & 1;      // 0..1 (col half: 64 cols each)

    // XCD-chunked bijective swizzle (NWG % 8 == 0); mb fastest so the 8
    // m-blocks sharing one 128-row W strip co-locate on one XCD's L2.
    const int bid = blockIdx.x;
    const int wg  = (bid & 7) * (NWG / 8) + (bid >> 3);
    const int mb  = wg % MB_CNT;
    const int nb  = wg / MB_CNT;

    // staging: per gload_lds instr a wave covers 16 rows of 64B; dest row =
    // base + (lane>>2), phys 16B-slot = lane&3. T2 swizzle phys =
    // logical ^ ((row>>1)&3) -> source slot = (lane&3) ^ ((lane>>3)&3).
    // Wave w stages A rows [w*64, w*64+64) (4 instr) and B rows
    // [w*32, w*32+32) (2 instr) -> 6 loads per wave per stage().
    const int lslot = (lane & 3) ^ ((lane >> 3) & 3);
    const signed char* srcA =
        Xq + (size_t)(mb * BM + wave * 64 + (lane >> 2)) * K_DIM + lslot * 16;
    const signed char* srcB =
        W8 + (size_t)(nb * BN + wave * 32 + (lane >> 2)) * K_DIM + lslot * 16;

    auto stage = [&](int b3, int k0) {   // k0 in BYTES along K
        #pragma unroll
        for (int j = 0; j < 4; ++j)
            gload_lds16(srcA + (size_t)(j * 16) * K_DIM + k0,
                        &ldsA[b3][wave * 64 + j * 16][0]);
        #pragma unroll
        for (int j = 0; j < 2; ++j)
            gload_lds16(srcB + (size_t)(j * 16) * K_DIM + k0,
                        &ldsB[b3][wave * 32 + j * 16][0]);
    };

    // frag reads: row = R0 + (lane&15); lane holds 16 consecutive i8
    // (K-group = lane>>4); phys 16B-octet = (lane>>4) ^ ((lane>>1)&3).
    const int physoff   = ((lane >> 4) ^ ((lane >> 1) & 3)) * 16;   // bytes
    const int arow_base = wr * 128 + (lane & 15);
    const int brow_base = wc * 64  + (lane & 15);

    i32x4 acc[8][4];
    #pragma unroll
    for (int i = 0; i < 8; ++i)
        #pragma unroll
        for (int j = 0; j < 4; ++j)
            acc[i][j] = i32x4{0, 0, 0, 0};

    // prologue: stage tiles 0,1 (12 loads); retire tile 0 (oldest 6); publish
    stage(0, 0);
    stage(1, BK);
    SCHED0;
    VMCNT(6);
    SCHED0;
    __builtin_amdgcn_s_barrier();
    SCHED0;

    i32x4 af[8], bfr[4];

#define READ_AB(B3) do { \
    _Pragma("unroll") \
    for (int mf = 0; mf < 8; ++mf) \
        af[mf] = *(const i32x4*)&ldsA[B3][arow_base + mf * 16][physoff]; \
    _Pragma("unroll") \
    for (int nf = 0; nf < 4; ++nf) \
        bfr[nf] = *(const i32x4*)&ldsB[B3][brow_base + nf * 16][physoff]; \
} while (0)
#define MFMA32() do { \
    __builtin_amdgcn_s_setprio(1); \
    _Pragma("unroll") \
    for (int mf = 0; mf < 8; ++mf) { \
        _Pragma("unroll") \
        for (int nf = 0; nf < 4; ++nf) \
            acc[mf][nf] = __builtin_amdgcn_mfma_i32_16x16x64_i8( \
                af[mf], bfr[nf], acc[mf][nf], 0, 0, 0); \
    } \
    __builtin_amdgcn_s_setprio(0); \
} while (0)

    for (int t = 0; t < NKT - 2; ++t) {   // t = 0..11
        const int cur = t % 3;
        READ_AB(cur);
        stage((t + 2) % 3, (t + 2) * BK);
        SCHED0;
        VMCNT(6);       // retires stage(t+1), issued at tile t-1
        LGKM0;          // my buf[t] reads drained before the barrier
        SCHED0;
        __builtin_amdgcn_s_barrier();   // publishes tile t+1; gates WAR
        SCHED0;
        MFMA32();
    }

    // t = NKT-2 = 12: no stage; drain tile NKT-1's batch
    {
        READ_AB((NKT - 2) % 3);
        SCHED0;
        VMCNT(0);
        LGKM0;
        SCHED0;
        __builtin_amdgcn_s_barrier();
        SCHED0;
        MFMA32();
    }
    // t = NKT-1 = 13: reads only (published at previous barrier)
    {
        READ_AB((NKT - 1) % 3);
        SCHED0;
        LGKM0;
        SCHED0;
        MFMA32();
    }

#undef READ_AB
#undef MFMA32

    // ---- LDS-coalesced epilogue ----
    // Reuse LDS as float[64][128] (32 KiB, fits in ldsA). 4 passes over
    // 64-row quarters. Writers: waves with wr == p>>1 use acc[(p&1)*4 ..].
    // Writes: (float)acc * Sw[n], XOR-swizzled pcol = col ^ (qw<<4).
    // Reads: f32x4 * Sx[row] -> full 128B-line global row stores.
    __syncthreads();   // all K-loop work fully drained

    float* lf = (float*)&ldsA[0][0][0];
    const int qw = lane >> 4;     // 0..3
    const int li = lane & 15;

    float scn[4];
    #pragma unroll
    for (int nf = 0; nf < 4; ++nf)
        scn[nf] = Sw[nb * BN + wc * 64 + nf * 16 + li];

    #pragma unroll
    for (int p = 0; p < 4; ++p) {
        if (p) __syncthreads();   // prev pass reads done before overwrite
        if (wr == (p >> 1)) {
            #pragma unroll
            for (int al = 0; al < 4; ++al) {
                const int a = (p & 1) * 4 + al;
                #pragma unroll
                for (int nf = 0; nf < 4; ++nf) {
                    #pragma unroll
                    for (int r = 0; r < 4; ++r) {
                        const int lr   = al * 16 + qw * 4 + r;   // 0..63
                        const int col  = wc * 64 + nf * 16 + li;
                        const int pcol = col ^ (qw << 4);
                        lf[lr * 128 + pcol] = (float)acc[a][nf][r] * scn[nf];
                    }
                }
            }
        }
        __syncthreads();
        #pragma unroll
        for (int i = 0; i < 8; ++i) {
            const int row = wave * 16 + i * 2 + (lane >> 5);   // 0..63
            const int q   = (row >> 2) & 3;
            const int pch = (lane & 31) ^ (q << 2);
            f32x4 v = *(const f32x4*)&lf[row * 128 + pch * 4];
            const size_t grow = (size_t)(mb * BM + p * 64 + row);
            const float sxr = Sx[grow];
            v *= sxr;
            const size_t gcol = (size_t)(nb * BN + (lane & 31) * 4);
            *(f32x4*)&O[grow * N_DIM + gcol] = v;
        }
    }
}

// ---------------- fallback: bf16 reg staging + in-loop convert ----------------

#define FBM 128
#define FBN 128
#define FBK 32
#define FNSTEPS (K_DIM / FBK)
#define FMB (M_DIM / FBM)
#define FNB (N_DIM / FBN)
#define FNWG (FMB * FNB)

__global__ __launch_bounds__(256, 2)
void lmhead_gemm_conv(const float* __restrict__ X,
                      const int* __restrict__ Wq,
                      const float* __restrict__ S,
                      float* __restrict__ O)
{
    __shared__ unsigned short Alds[2][FBM][FBK];
    __shared__ unsigned short Blds2[2][FBN][FBK];

    const int tid  = threadIdx.x;
    const int lane = tid & 63;
    const int wave = tid >> 6;
    const int wr   = wave >> 1;
    const int wc   = wave & 1;

    const int bid = blockIdx.x;
    const int wg  = (bid & 7) * (FNWG / 8) + (bid >> 3);
    const int mb  = wg % FMB;
    const int nb  = wg / FMB;

    const int srow = tid >> 1;
    const int skh  = (tid & 1) * 16;

    const float* aptr = X  + (size_t)(mb * FBM + srow) * K_DIM + skh;
    const int*   wptr = Wq + (size_t)(nb * FBN + srow) * K_DIM + skh;

    f32x4 av[4];
    i32x4 wv[4];

    auto load_tiles = [&](int k0) {
        const f32x4* ap = (const f32x4*)(aptr + k0);
        const i32x4* wp = (const i32x4*)(wptr + k0);
        av[0] = ap[0]; av[1] = ap[1]; av[2] = ap[2]; av[3] = ap[3];
        wv[0] = wp[0]; wv[1] = wp[1]; wv[2] = wp[2]; wv[3] = wp[3];
    };

    auto stage = [&](int buf) {
        unsigned int apk[8], wpk[8];
        #pragma unroll
        for (int i = 0; i < 8; ++i) {
            apk[i] = pack2(av[(2*i) >> 2][(2*i) & 3], av[(2*i+1) >> 2][(2*i+1) & 3]);
            wpk[i] = pack2((float)wv[(2*i) >> 2][(2*i) & 3], (float)wv[(2*i+1) >> 2][(2*i+1) & 3]);
        }
        *(u32x4*)&Alds[buf][srow][skh]      = u32x4{apk[0], apk[1], apk[2], apk[3]};
        *(u32x4*)&Alds[buf][srow][skh + 8]  = u32x4{apk[4], apk[5], apk[6], apk[7]};
        *(u32x4*)&Blds2[buf][srow][skh]     = u32x4{wpk[0], wpk[1], wpk[2], wpk[3]};
        *(u32x4*)&Blds2[buf][srow][skh + 8] = u32x4{wpk[4], wpk[5], wpk[6], wpk[7]};
    };

    f32x4 acc[4][4];
    #pragma unroll
    for (int i = 0; i < 4; ++i)
        #pragma unroll
        for (int j = 0; j < 4; ++j)
            acc[i][j] = f32x4{0.f, 0.f, 0.f, 0.f};

    load_tiles(0);
    stage(0);
    __syncthreads();

    int cur = 0;
    for (int s = 0; s < FNSTEPS; ++s) {
        if (s + 1 < FNSTEPS) load_tiles((s + 1) * FBK);

        bf16x8 af[4], bfr[4];
        const int arow = wr * 64 + (lane & 15);
        const int brow = wc * 64 + (lane & 15);
        const int kb   = (lane >> 4) * 8;
        #pragma unroll
        for (int mf = 0; mf < 4; ++mf)
            af[mf] = *(const bf16x8*)&Alds[cur][arow + mf * 16][kb];
        #pragma unroll
        for (int nf = 0; nf < 4; ++nf)
            bfr[nf] = *(const bf16x8*)&Blds2[cur][brow + nf * 16][kb];

        #pragma unroll
        for (int mf = 0; mf < 4; ++mf)
            #pragma unroll
            for (int nf = 0; nf < 4; ++nf)
                acc[mf][nf] = __builtin_amdgcn_mfma_f32_16x16x32_bf16(
                    af[mf], bfr[nf], acc[mf][nf], 0, 0, 0);

        if (s + 1 < FNSTEPS) stage(cur ^ 1);
        __syncthreads();
        cur ^= 1;
    }

    #pragma unroll
    for (int nf = 0; nf < 4; ++nf) {
        const int n = nb * FBN + wc * 64 + nf * 16 + (lane & 15);
        const float sc = S[n];
        #pragma unroll
        for (int mf = 0; mf < 4; ++mf) {
            const int m0 = mb * FBM + wr * 64 + mf * 16 + ((lane >> 4) << 2);
            #pragma unroll
            for (int r = 0; r < 4; ++r)
                O[(size_t)(m0 + r) * N_DIM + n] = acc[mf][nf][r] * sc;
        }
    }
}

// ---------------- launch ----------------

extern "C" void kernel_launch(void* const* d_in, const int* in_sizes, int n_in,
                              void* d_out, int out_size, void* d_ws, size_t ws_size,
                              hipStream_t stream) {
    const float* X  = (const float*)d_in[0];
    const int*   Wq = (const int*)d_in[1];
    const float* S  = (const float*)d_in[2];
    float*       O  = (float*)d_out;

    const size_t XQ_BYTES = (size_t)M_DIM * K_DIM;            // 1,835,008
    const size_t SX_BYTES = (size_t)M_DIM * sizeof(float);    // 8,192
    const size_t W8_BYTES = (size_t)N_DIM * K_DIM;            // 136,134,656

    if (ws_size >= XQ_BYTES + SX_BYTES + W8_BYTES) {
        signed char* xq = (signed char*)d_ws;
        float*       sx = (float*)((char*)d_ws + XQ_BYTES);
        signed char* w8 = (signed char*)((char*)d_ws + XQ_BYTES + SX_BYTES);
        quant_x_kernel<<<M_DIM / 4, 256, 0, stream>>>(X, xq, sx);
        cvt_w8_kernel<<<2048, 256, 0, stream>>>(Wq, w8);
        lmhead_gemm_i8<<<NWG, 256, 0, stream>>>(xq, w8, S, sx, O);
    } else {
        lmhead_gemm_conv<<<FNWG, 256, 0, stream>>>(X, Wq, S, O);
    }
}